// Round 1
// baseline (210.582 us; speedup 1.0000x reference)
//
#include <hip/hip_runtime.h>
#include <math.h>

#define B_SZ 4
#define LSEQ 2048
#define DDIM 768
#define NST  16

// ---------------- K1: projections Bp = x@Wb.T+bb, C = x@Wc.T+bc, s1 = x@W1.T+b1
// block = 256 threads, TB=8 rows of x staged in LDS; wave-per-dot with shfl reduce.
__global__ __launch_bounds__(256) void proj_kernel(
    const float* __restrict__ x,
    const float* __restrict__ Wb, const float* __restrict__ bb,
    const float* __restrict__ Wc, const float* __restrict__ bc,
    const float* __restrict__ W1, const float* __restrict__ b1,
    float* __restrict__ Bp, float* __restrict__ Cc, float* __restrict__ s1)
{
    const int TB = 8;
    __shared__ float xs[TB * DDIM];
    const int row0 = blockIdx.x * TB;
    const int tid = threadIdx.x;
    for (int i = tid; i < TB * DDIM; i += 256)
        xs[i] = x[(size_t)row0 * DDIM + i];
    __syncthreads();

    const int wave = tid >> 6, lane = tid & 63;
    for (int idx = wave; idx < TB * 33; idx += 4) {
        const int r = idx / 33, j = idx % 33;
        const float* wrow = (j < 16) ? (Wb + j * DDIM)
                          : (j < 32) ? (Wc + (j - 16) * DDIM)
                                     : W1;
        const float* xr = xs + r * DDIM;
        float acc = 0.f;
        #pragma unroll
        for (int k = 0; k < DDIM / 64; ++k)
            acc = fmaf(xr[k * 64 + lane], wrow[k * 64 + lane], acc);
        #pragma unroll
        for (int off = 32; off > 0; off >>= 1)
            acc += __shfl_xor(acc, off, 64);
        if (lane == 0) {
            const int row = row0 + r;
            if (j < 16)      Bp[(size_t)row * NST + j]        = acc + bb[j];
            else if (j < 32) Cc[(size_t)row * NST + (j - 16)] = acc + bc[j - 16];
            else             s1[row]                          = acc + b1[0];
        }
    }
}

__device__ __forceinline__ float softplus_f(float z) {
    // stable: max(z,0) + log1p(exp(-|z|))
    float t = __expf(-fabsf(z));
    return fmaxf(z, 0.f) + __logf(1.f + t);
}

// ---------------- K2: per-chunk aggregates P = prod(dA), Q = local scan end state
// grid = (D/256, NC, B); thread owns one d, 16 states in registers.
__global__ __launch_bounds__(256) void pass1_kernel(
    const float* __restrict__ x, const float* __restrict__ A_log,
    const float* __restrict__ Wd, const float* __restrict__ bd,
    const float* __restrict__ Bp, const float* __restrict__ s1,
    float* __restrict__ P, float* __restrict__ Q, int NC, int CS)
{
    extern __shared__ float sm[];           // sB[CS*16] + sS1[CS]
    float* sB  = sm;
    float* sS1 = sm + CS * NST;
    const int tid = threadIdx.x;
    const int d = blockIdx.x * 256 + tid;
    const int c = blockIdx.y, b = blockIdx.z;
    const int l0 = c * CS;
    const int rowbase = b * LSEQ + l0;
    for (int i = tid; i < CS * NST; i += 256) sB[i]  = Bp[(size_t)rowbase * NST + i];
    for (int i = tid; i < CS;       i += 256) sS1[i] = s1[rowbase + i];
    __syncthreads();

    const float wd = Wd[d], bdv = bd[d];
    float acoef[NST];
    #pragma unroll
    for (int n = 0; n < NST; ++n) acoef[n] = -__expf(A_log[d * NST + n]);

    float h[NST], p[NST];
    #pragma unroll
    for (int n = 0; n < NST; ++n) { h[n] = 0.f; p[n] = 1.f; }

    const float* xp = x + (size_t)rowbase * DDIM + d;
    float xv = xp[0];
    for (int l = 0; l < CS; ++l) {
        float xnext = (l + 1 < CS) ? xp[(size_t)(l + 1) * DDIM] : 0.f;
        float delta = softplus_f(fmaf(sS1[l], wd, bdv));
        float dx = delta * xv;
        #pragma unroll
        for (int n = 0; n < NST; ++n) {
            float e = __expf(delta * acoef[n]);
            h[n] = fmaf(e, h[n], dx * sB[l * NST + n]);
            p[n] *= e;
        }
        xv = xnext;
    }
    const size_t gbase = (((size_t)b * NC + c) * DDIM + d) * NST;
    #pragma unroll
    for (int n = 0; n < NST; ++n) { P[gbase + n] = p[n]; Q[gbase + n] = h[n]; }
}

// ---------------- K3: sequential combine over chunks -> Hin[b][c][d][n]
__global__ __launch_bounds__(256) void combine_kernel(
    const float* __restrict__ P, const float* __restrict__ Q,
    float* __restrict__ Hin, int NC)
{
    const int idx = blockIdx.x * 256 + threadIdx.x;   // over B*D*N = 49152
    const int b = idx / (DDIM * NST);
    const int r = idx % (DDIM * NST);
    float h = 0.f;
    for (int c = 0; c < NC; ++c) {
        const size_t g = ((size_t)(b * NC + c)) * (DDIM * NST) + r;
        Hin[g] = h;
        h = fmaf(P[g], h, Q[g]);
    }
}

// ---------------- K4: final scan seeded with Hin, emit y
__global__ __launch_bounds__(256) void pass2_kernel(
    const float* __restrict__ x, const float* __restrict__ A_log,
    const float* __restrict__ Wd, const float* __restrict__ bd,
    const float* __restrict__ Bp, const float* __restrict__ Cc,
    const float* __restrict__ s1, const float* __restrict__ Hin,
    float* __restrict__ out, int NC, int CS)
{
    extern __shared__ float sm[];           // sB[CS*16] + sC[CS*16] + sS1[CS]
    float* sB  = sm;
    float* sC  = sm + CS * NST;
    float* sS1 = sm + 2 * CS * NST;
    const int tid = threadIdx.x;
    const int d = blockIdx.x * 256 + tid;
    const int c = blockIdx.y, b = blockIdx.z;
    const int l0 = c * CS;
    const int rowbase = b * LSEQ + l0;
    for (int i = tid; i < CS * NST; i += 256) {
        sB[i] = Bp[(size_t)rowbase * NST + i];
        sC[i] = Cc[(size_t)rowbase * NST + i];
    }
    for (int i = tid; i < CS; i += 256) sS1[i] = s1[rowbase + i];
    __syncthreads();

    const float wd = Wd[d], bdv = bd[d];
    float acoef[NST];
    #pragma unroll
    for (int n = 0; n < NST; ++n) acoef[n] = -__expf(A_log[d * NST + n]);

    float h[NST];
    const size_t gbase = (((size_t)b * NC + c) * DDIM + d) * NST;
    #pragma unroll
    for (int n = 0; n < NST; ++n) h[n] = Hin[gbase + n];

    const float* xp = x + (size_t)rowbase * DDIM + d;
    float* yp = out + (size_t)rowbase * DDIM + d;
    float xv = xp[0];
    for (int l = 0; l < CS; ++l) {
        float xnext = (l + 1 < CS) ? xp[(size_t)(l + 1) * DDIM] : 0.f;
        float delta = softplus_f(fmaf(sS1[l], wd, bdv));
        float dx = delta * xv;
        float y = 0.f;
        #pragma unroll
        for (int n = 0; n < NST; ++n) {
            float e = __expf(delta * acoef[n]);
            h[n] = fmaf(e, h[n], dx * sB[l * NST + n]);
            y = fmaf(h[n], sC[l * NST + n], y);
        }
        yp[(size_t)l * DDIM] = y;
        xv = xnext;
    }
}

extern "C" void kernel_launch(void* const* d_in, const int* in_sizes, int n_in,
                              void* d_out, int out_size, void* d_ws, size_t ws_size,
                              hipStream_t stream) {
    const float* x     = (const float*)d_in[0];
    const float* A_log = (const float*)d_in[1];
    const float* Wb    = (const float*)d_in[2];
    const float* bb    = (const float*)d_in[3];
    const float* Wc    = (const float*)d_in[4];
    const float* bc    = (const float*)d_in[5];
    const float* W1    = (const float*)d_in[6];
    const float* b1    = (const float*)d_in[7];
    const float* Wd    = (const float*)d_in[8];
    const float* bd    = (const float*)d_in[9];
    float* out = (float*)d_out;

    float* ws = (float*)d_ws;
    const size_t BpN = (size_t)B_SZ * LSEQ * NST;   // 131072
    const size_t s1N = (size_t)B_SZ * LSEQ;         // 8192

    // pick chunk count that fits workspace
    int NC = 64;
    while (NC > 1) {
        size_t need = (2 * BpN + s1N + 3 * (size_t)B_SZ * NC * DDIM * NST) * sizeof(float);
        if (need <= ws_size) break;
        NC >>= 1;
    }
    const int CS = LSEQ / NC;

    float* Bp  = ws;
    float* Cc  = ws + BpN;
    float* s1  = ws + 2 * BpN;
    float* P   = ws + 2 * BpN + s1N;
    const size_t agg = (size_t)B_SZ * NC * DDIM * NST;
    float* Q   = P + agg;
    float* Hin = Q + agg;

    proj_kernel<<<B_SZ * LSEQ / 8, 256, 0, stream>>>(x, Wb, bb, Wc, bc, W1, b1, Bp, Cc, s1);

    dim3 gscan(DDIM / 256, NC, B_SZ);
    size_t sm1 = (size_t)(CS * NST + CS) * sizeof(float);
    pass1_kernel<<<gscan, 256, sm1, stream>>>(x, A_log, Wd, bd, Bp, s1, P, Q, NC, CS);

    combine_kernel<<<B_SZ * DDIM * NST / 256, 256, 0, stream>>>(P, Q, Hin, NC);

    size_t sm2 = (size_t)(2 * CS * NST + CS) * sizeof(float);
    pass2_kernel<<<gscan, 256, sm2, stream>>>(x, A_log, Wd, bd, Bp, Cc, s1, Hin, out, NC, CS);
}

// Round 2
// 196.029 us; speedup vs baseline: 1.0742x; 1.0742x over previous
//
#include <hip/hip_runtime.h>
#include <math.h>

#define B_SZ 4
#define LSEQ 2048
#define DDIM 768
#define NST  16
#define NROW (B_SZ * LSEQ)      // 8192
#define NJ   33                 // 16 B + 16 C + 1 s1

// ================= projection: partials over K-splits =================
#define KSPLIT 8
#define KCHUNK (DDIM / KSPLIT)  // 96
#define KT 32                   // k sub-tile staged in LDS

__global__ __launch_bounds__(256) void proj_part_kernel(
    const float* __restrict__ x,
    const float* __restrict__ Wb, const float* __restrict__ Wc,
    const float* __restrict__ W1, float* __restrict__ part)
{
    __shared__ float xs[256 * (KT + 1)];
    const int tid = threadIdx.x;
    const int row0 = blockIdx.x * 256;
    const int s = blockIdx.y;
    const int k0 = s * KCHUNK;

    float acc[NJ];
    #pragma unroll
    for (int j = 0; j < NJ; ++j) acc[j] = 0.f;

    for (int sub = 0; sub < KCHUNK / KT; ++sub) {
        const int kb = k0 + sub * KT;
        __syncthreads();
        // stage 256 rows x KT floats, coalesced float4 global loads
        for (int i = tid; i < 256 * (KT / 4); i += 256) {
            const int r = i / (KT / 4);
            const int kq = i % (KT / 4);
            const float4 v = *(const float4*)(x + (size_t)(row0 + r) * DDIM + kb + kq * 4);
            float* dst = xs + r * (KT + 1) + kq * 4;
            dst[0] = v.x; dst[1] = v.y; dst[2] = v.z; dst[3] = v.w;
        }
        __syncthreads();
        float xr[KT];
        #pragma unroll
        for (int k = 0; k < KT; ++k) xr[k] = xs[tid * (KT + 1) + k];
        #pragma unroll
        for (int j = 0; j < NJ; ++j) {
            // j is an unrolled constant -> pointer folds at compile time;
            // wk[k] is wave-uniform -> s_load into SGPRs (v_fma takes 1 SGPR src)
            const float* wr = (j < 16) ? (Wb + j * DDIM)
                            : (j < 32) ? (Wc + (j - 16) * DDIM)
                                       : W1;
            const float* wk = wr + kb;
            #pragma unroll
            for (int k = 0; k < KT; ++k) acc[j] = fmaf(xr[k], wk[k], acc[j]);
        }
    }
    #pragma unroll
    for (int j = 0; j < NJ; ++j)
        part[((size_t)s * NJ + j) * NROW + row0 + tid] = acc[j];
}

__global__ __launch_bounds__(256) void proj_reduce_kernel(
    const float* __restrict__ part,
    const float* __restrict__ bb, const float* __restrict__ bc,
    const float* __restrict__ b1,
    float* __restrict__ Bp, float* __restrict__ Cc, float* __restrict__ s1)
{
    const int idx = blockIdx.x * 256 + threadIdx.x;   // over NJ*NROW
    const int j = idx / NROW;
    const int row = idx % NROW;
    float a = 0.f;
    #pragma unroll
    for (int s = 0; s < KSPLIT; ++s)
        a += part[((size_t)s * NJ + j) * NROW + row];
    if (j < 16)      Bp[(size_t)row * NST + j] = a + bb[j];
    else if (j < 32) Cc[(size_t)row * NST + (j - 16)] = a + bc[j - 16];
    else             s1[row] = a + b1[0];
}

// ================= scan =================
__device__ __forceinline__ float softplus_f(float z) {
    float t = __expf(-fabsf(z));
    return fmaxf(z, 0.f) + __logf(1.f + t);
}

// e[n] = p^(n+1), depth-4 multiply tree
__device__ __forceinline__ void powers16(float p, float* e) {
    e[0] = p;
    e[1] = p * p;
    e[2] = e[1] * p;
    e[3] = e[1] * e[1];
    e[4] = e[3] * p;
    e[5] = e[3] * e[1];
    e[6] = e[3] * e[2];
    e[7] = e[3] * e[3];
    e[8] = e[7] * p;
    e[9] = e[7] * e[1];
    e[10] = e[7] * e[2];
    e[11] = e[7] * e[3];
    e[12] = e[7] * e[4];
    e[13] = e[7] * e[5];
    e[14] = e[7] * e[6];
    e[15] = e[7] * e[7];
}

__device__ __forceinline__ bool a_structured(const float* acoef) {
    // A_log = log(tile(arange(1..16))) => acoef[n] == (n+1)*acoef[0]
    bool st = true;
    #pragma unroll
    for (int n = 0; n < NST; ++n)
        st = st && (fabsf(acoef[n] - (float)(n + 1) * acoef[0]) <= 1e-5f * fabsf(acoef[n]));
    return __all(st) != 0;
}

template <int CS>
__global__ __launch_bounds__(256) void pass1_kernel(
    const float* __restrict__ x, const float* __restrict__ A_log,
    const float* __restrict__ Wd, const float* __restrict__ bd,
    const float* __restrict__ Bp, const float* __restrict__ s1,
    float* __restrict__ P, float* __restrict__ Q)
{
    const int tid = threadIdx.x;
    const int d = blockIdx.x * 256 + tid;
    const int c = blockIdx.y, b = blockIdx.z;
    const int NC = gridDim.y;
    const int rowbase = b * LSEQ + c * CS;

    const float wd = Wd[d], bdv = bd[d];
    float acoef[NST];
    #pragma unroll
    for (int n = 0; n < NST; ++n) acoef[n] = -__expf(A_log[d * NST + n]);
    const float a0 = acoef[0];
    const bool structured = a_structured(acoef);

    const float4* B4 = (const float4*)(Bp + (size_t)rowbase * NST);  // uniform -> s_load
    const float* s1p = s1 + rowbase;                                  // uniform -> s_load
    const float* xp = x + (size_t)rowbase * DDIM + d;

    float h[NST];
    #pragma unroll
    for (int n = 0; n < NST; ++n) h[n] = 0.f;
    float S = 0.f;

    if (structured) {
        #pragma unroll 4
        for (int l = 0; l < CS; ++l) {
            const float delta = softplus_f(fmaf(s1p[l], wd, bdv));
            S += delta;
            float e[NST];
            powers16(__expf(delta * a0), e);
            const float dx = delta * xp[(size_t)l * DDIM];
            const float4 b0 = B4[l * 4 + 0], b1v = B4[l * 4 + 1];
            const float4 b2 = B4[l * 4 + 2], b3v = B4[l * 4 + 3];
            const float bv[NST] = {b0.x, b0.y, b0.z, b0.w, b1v.x, b1v.y, b1v.z, b1v.w,
                                   b2.x, b2.y, b2.z, b2.w, b3v.x, b3v.y, b3v.z, b3v.w};
            #pragma unroll
            for (int n = 0; n < NST; ++n) h[n] = fmaf(e[n], h[n], dx * bv[n]);
        }
    } else {
        #pragma unroll 4
        for (int l = 0; l < CS; ++l) {
            const float delta = softplus_f(fmaf(s1p[l], wd, bdv));
            S += delta;
            float e[NST];
            #pragma unroll
            for (int n = 0; n < NST; ++n) e[n] = __expf(delta * acoef[n]);
            const float dx = delta * xp[(size_t)l * DDIM];
            const float4 b0 = B4[l * 4 + 0], b1v = B4[l * 4 + 1];
            const float4 b2 = B4[l * 4 + 2], b3v = B4[l * 4 + 3];
            const float bv[NST] = {b0.x, b0.y, b0.z, b0.w, b1v.x, b1v.y, b1v.z, b1v.w,
                                   b2.x, b2.y, b2.z, b2.w, b3v.x, b3v.y, b3v.z, b3v.w};
            #pragma unroll
            for (int n = 0; n < NST; ++n) h[n] = fmaf(e[n], h[n], dx * bv[n]);
        }
    }
    // P[n] = prod_l exp(acoef[n]*delta_l) = exp(acoef[n] * S)  (exact identity)
    const size_t gbase = (((size_t)b * NC + c) * DDIM + d) * NST;
    float4* P4 = (float4*)(P + gbase);
    float4* Q4 = (float4*)(Q + gbase);
    float pv[NST];
    #pragma unroll
    for (int n = 0; n < NST; ++n) pv[n] = __expf(acoef[n] * S);
    #pragma unroll
    for (int q = 0; q < 4; ++q) {
        P4[q] = make_float4(pv[q * 4], pv[q * 4 + 1], pv[q * 4 + 2], pv[q * 4 + 3]);
        Q4[q] = make_float4(h[q * 4], h[q * 4 + 1], h[q * 4 + 2], h[q * 4 + 3]);
    }
}

__global__ __launch_bounds__(256) void combine_kernel(
    const float* __restrict__ P, const float* __restrict__ Q,
    float* __restrict__ Hin, int NC)
{
    const int idx = blockIdx.x * 256 + threadIdx.x;   // over B*D*N
    const int b = idx / (DDIM * NST);
    const int r = idx % (DDIM * NST);
    float h = 0.f;
    #pragma unroll 4
    for (int c = 0; c < NC; ++c) {
        const size_t g = ((size_t)(b * NC + c)) * (DDIM * NST) + r;
        Hin[g] = h;
        h = fmaf(P[g], h, Q[g]);
    }
}

template <int CS>
__global__ __launch_bounds__(256) void pass2_kernel(
    const float* __restrict__ x, const float* __restrict__ A_log,
    const float* __restrict__ Wd, const float* __restrict__ bd,
    const float* __restrict__ Bp, const float* __restrict__ Cc,
    const float* __restrict__ s1, const float* __restrict__ Hin,
    float* __restrict__ out)
{
    const int tid = threadIdx.x;
    const int d = blockIdx.x * 256 + tid;
    const int c = blockIdx.y, b = blockIdx.z;
    const int NC = gridDim.y;
    const int rowbase = b * LSEQ + c * CS;

    const float wd = Wd[d], bdv = bd[d];
    float acoef[NST];
    #pragma unroll
    for (int n = 0; n < NST; ++n) acoef[n] = -__expf(A_log[d * NST + n]);
    const float a0 = acoef[0];
    const bool structured = a_structured(acoef);

    const float4* B4 = (const float4*)(Bp + (size_t)rowbase * NST);
    const float4* C4 = (const float4*)(Cc + (size_t)rowbase * NST);
    const float* s1p = s1 + rowbase;
    const float* xp = x + (size_t)rowbase * DDIM + d;
    float* yp = out + (size_t)rowbase * DDIM + d;

    float h[NST];
    const size_t gbase = (((size_t)b * NC + c) * DDIM + d) * NST;
    const float4* H4 = (const float4*)(Hin + gbase);
    #pragma unroll
    for (int q = 0; q < 4; ++q) {
        const float4 hv = H4[q];
        h[q * 4] = hv.x; h[q * 4 + 1] = hv.y; h[q * 4 + 2] = hv.z; h[q * 4 + 3] = hv.w;
    }

    if (structured) {
        #pragma unroll 4
        for (int l = 0; l < CS; ++l) {
            const float delta = softplus_f(fmaf(s1p[l], wd, bdv));
            float e[NST];
            powers16(__expf(delta * a0), e);
            const float dx = delta * xp[(size_t)l * DDIM];
            const float4 b0 = B4[l * 4 + 0], b1v = B4[l * 4 + 1];
            const float4 b2 = B4[l * 4 + 2], b3v = B4[l * 4 + 3];
            const float4 c0 = C4[l * 4 + 0], c1v = C4[l * 4 + 1];
            const float4 c2 = C4[l * 4 + 2], c3v = C4[l * 4 + 3];
            const float bv[NST] = {b0.x, b0.y, b0.z, b0.w, b1v.x, b1v.y, b1v.z, b1v.w,
                                   b2.x, b2.y, b2.z, b2.w, b3v.x, b3v.y, b3v.z, b3v.w};
            const float cv[NST] = {c0.x, c0.y, c0.z, c0.w, c1v.x, c1v.y, c1v.z, c1v.w,
                                   c2.x, c2.y, c2.z, c2.w, c3v.x, c3v.y, c3v.z, c3v.w};
            float y = 0.f;
            #pragma unroll
            for (int n = 0; n < NST; ++n) {
                h[n] = fmaf(e[n], h[n], dx * bv[n]);
                y = fmaf(h[n], cv[n], y);
            }
            yp[(size_t)l * DDIM] = y;
        }
    } else {
        #pragma unroll 4
        for (int l = 0; l < CS; ++l) {
            const float delta = softplus_f(fmaf(s1p[l], wd, bdv));
            float e[NST];
            #pragma unroll
            for (int n = 0; n < NST; ++n) e[n] = __expf(delta * acoef[n]);
            const float dx = delta * xp[(size_t)l * DDIM];
            const float4 b0 = B4[l * 4 + 0], b1v = B4[l * 4 + 1];
            const float4 b2 = B4[l * 4 + 2], b3v = B4[l * 4 + 3];
            const float4 c0 = C4[l * 4 + 0], c1v = C4[l * 4 + 1];
            const float4 c2 = C4[l * 4 + 2], c3v = C4[l * 4 + 3];
            const float bv[NST] = {b0.x, b0.y, b0.z, b0.w, b1v.x, b1v.y, b1v.z, b1v.w,
                                   b2.x, b2.y, b2.z, b2.w, b3v.x, b3v.y, b3v.z, b3v.w};
            const float cv[NST] = {c0.x, c0.y, c0.z, c0.w, c1v.x, c1v.y, c1v.z, c1v.w,
                                   c2.x, c2.y, c2.z, c2.w, c3v.x, c3v.y, c3v.z, c3v.w};
            float y = 0.f;
            #pragma unroll
            for (int n = 0; n < NST; ++n) {
                h[n] = fmaf(e[n], h[n], dx * bv[n]);
                y = fmaf(h[n], cv[n], y);
            }
            yp[(size_t)l * DDIM] = y;
        }
    }
}

extern "C" void kernel_launch(void* const* d_in, const int* in_sizes, int n_in,
                              void* d_out, int out_size, void* d_ws, size_t ws_size,
                              hipStream_t stream) {
    const float* x     = (const float*)d_in[0];
    const float* A_log = (const float*)d_in[1];
    const float* Wb    = (const float*)d_in[2];
    const float* bb    = (const float*)d_in[3];
    const float* Wc    = (const float*)d_in[4];
    const float* bc    = (const float*)d_in[5];
    const float* W1    = (const float*)d_in[6];
    const float* b1    = (const float*)d_in[7];
    const float* Wd    = (const float*)d_in[8];
    const float* bd    = (const float*)d_in[9];
    float* out = (float*)d_out;

    float* ws = (float*)d_ws;
    const size_t partN = (size_t)KSPLIT * NJ * NROW;   // 2,162,688
    const size_t BpN = (size_t)NROW * NST;             // 131072
    const size_t s1N = (size_t)NROW;                   // 8192

    int NC = 64;
    while (NC > 16) {
        size_t need = (partN + 2 * BpN + s1N + 3 * (size_t)B_SZ * NC * DDIM * NST) * sizeof(float);
        if (need <= ws_size) break;
        NC >>= 1;
    }
    const int CS = LSEQ / NC;

    float* part = ws;
    float* Bp   = part + partN;
    float* Cc   = Bp + BpN;
    float* s1   = Cc + BpN;
    float* P    = s1 + s1N;
    const size_t agg = (size_t)B_SZ * NC * DDIM * NST;
    float* Q    = P + agg;
    float* Hin  = Q + agg;

    dim3 gproj(NROW / 256, KSPLIT);
    proj_part_kernel<<<gproj, 256, 0, stream>>>(x, Wb, Wc, W1, part);
    proj_reduce_kernel<<<(NJ * NROW) / 256, 256, 0, stream>>>(part, bb, bc, b1, Bp, Cc, s1);

    dim3 gscan(DDIM / 256, NC, B_SZ);
    if (CS == 32)
        pass1_kernel<32><<<gscan, 256, 0, stream>>>(x, A_log, Wd, bd, Bp, s1, P, Q);
    else if (CS == 64)
        pass1_kernel<64><<<gscan, 256, 0, stream>>>(x, A_log, Wd, bd, Bp, s1, P, Q);
    else
        pass1_kernel<128><<<gscan, 256, 0, stream>>>(x, A_log, Wd, bd, Bp, s1, P, Q);

    combine_kernel<<<(B_SZ * DDIM * NST) / 256, 256, 0, stream>>>(P, Q, Hin, NC);

    if (CS == 32)
        pass2_kernel<32><<<gscan, 256, 0, stream>>>(x, A_log, Wd, bd, Bp, Cc, s1, Hin, out);
    else if (CS == 64)
        pass2_kernel<64><<<gscan, 256, 0, stream>>>(x, A_log, Wd, bd, Bp, Cc, s1, Hin, out);
    else
        pass2_kernel<128><<<gscan, 256, 0, stream>>>(x, A_log, Wd, bd, Bp, Cc, s1, Hin, out);
}

// Round 3
// 160.581 us; speedup vs baseline: 1.3114x; 1.2207x over previous
//
#include <hip/hip_runtime.h>
#include <math.h>

#define B_SZ 4
#define LSEQ 2048
#define DDIM 768
#define NST  16
#define NROW (B_SZ * LSEQ)      // 8192
#define NJ   33                 // 16 B + 16 C + 1 s1

// ================= projection =================
#define KSPLIT 16
#define KCHUNK (DDIM / KSPLIT)  // 48

// grid (32, 16), block 256: thread = one row, one K-chunk of 48.
__global__ __launch_bounds__(256) void proj_part_kernel(
    const float* __restrict__ x,
    const float* __restrict__ Wb, const float* __restrict__ Wc,
    const float* __restrict__ W1, float* __restrict__ part)
{
    __shared__ float xs[256 * (KCHUNK + 1)];   // stride 49: conflict-free reads
    const int tid = threadIdx.x;
    const int row0 = blockIdx.x * 256;
    const int s = blockIdx.y;
    const int k0 = s * KCHUNK;

    // stage 256 rows x 48 floats, coalesced float4 loads
    for (int i = tid; i < 256 * (KCHUNK / 4); i += 256) {
        const int r = i / (KCHUNK / 4);
        const int kq = i % (KCHUNK / 4);
        const float4 v = *(const float4*)(x + (size_t)(row0 + r) * DDIM + k0 + kq * 4);
        float* dst = xs + r * (KCHUNK + 1) + kq * 4;
        dst[0] = v.x; dst[1] = v.y; dst[2] = v.z; dst[3] = v.w;
    }
    __syncthreads();

    float xr[KCHUNK];
    #pragma unroll
    for (int k = 0; k < KCHUNK; ++k) xr[k] = xs[tid * (KCHUNK + 1) + k];

    float acc[NJ];
    #pragma unroll
    for (int j = 0; j < NJ; ++j) acc[j] = 0.f;

    #pragma unroll
    for (int j = 0; j < NJ; ++j) {
        const float* wr = (j < 16) ? (Wb + j * DDIM)
                        : (j < 32) ? (Wc + (j - 16) * DDIM)
                                   : W1;
        const float* wk = wr + k0;   // wave-uniform -> s_load
        #pragma unroll
        for (int k = 0; k < KCHUNK; ++k) acc[j] = fmaf(xr[k], wk[k], acc[j]);
    }
    #pragma unroll
    for (int j = 0; j < NJ; ++j)
        part[((size_t)s * NJ + j) * NROW + row0 + tid] = acc[j];
}

__global__ __launch_bounds__(256) void proj_reduce_kernel(
    const float* __restrict__ part,
    const float* __restrict__ bb, const float* __restrict__ bc,
    const float* __restrict__ b1,
    float* __restrict__ Bp, float* __restrict__ Cc, float* __restrict__ s1)
{
    const int idx = blockIdx.x * 256 + threadIdx.x;   // over NJ*NROW
    const int j = idx / NROW;
    const int row = idx % NROW;
    float a = 0.f;
    #pragma unroll
    for (int s = 0; s < KSPLIT; ++s)
        a += part[((size_t)s * NJ + j) * NROW + row];
    if (j < 16)      Bp[(size_t)row * NST + j] = a + bb[j];
    else if (j < 32) Cc[(size_t)row * NST + (j - 16)] = a + bc[j - 16];
    else             s1[row] = a + b1[0];
}

// ================= scan =================
__device__ __forceinline__ float softplus_f(float z) {
    float t = __expf(-fabsf(z));
    return fmaxf(z, 0.f) + __logf(1.f + t);
}

// e[n] = p^(n+1), depth-4 multiply tree
__device__ __forceinline__ void powers16(float p, float* e) {
    e[0] = p;      e[1] = p * p;      e[2] = e[1] * p;   e[3] = e[1] * e[1];
    e[4] = e[3] * p;  e[5] = e[3] * e[1];  e[6] = e[3] * e[2];  e[7] = e[3] * e[3];
    e[8] = e[7] * p;  e[9] = e[7] * e[1];  e[10] = e[7] * e[2]; e[11] = e[7] * e[3];
    e[12] = e[7] * e[4]; e[13] = e[7] * e[5]; e[14] = e[7] * e[6]; e[15] = e[7] * e[7];
}

__device__ __forceinline__ bool a_structured(const float* acoef) {
    bool st = true;
    #pragma unroll
    for (int n = 0; n < NST; ++n)
        st = st && (fabsf(acoef[n] - (float)(n + 1) * acoef[0]) <= 1e-5f * fabsf(acoef[n]));
    return __all(st) != 0;
}

template <int CS>
__global__ __launch_bounds__(256) void pass1_kernel(
    const float* __restrict__ x, const float* __restrict__ A_log,
    const float* __restrict__ Wd, const float* __restrict__ bd,
    const float* __restrict__ Bp, const float* __restrict__ s1,
    float* __restrict__ Ssum, float* __restrict__ Q)
{
    const int tid = threadIdx.x;
    const int d = blockIdx.x * 256 + tid;
    const int c = blockIdx.y, b = blockIdx.z;
    const int NC = gridDim.y;
    const int rowbase = b * LSEQ + c * CS;

    const float wd = Wd[d], bdv = bd[d];
    float acoef[NST];
    #pragma unroll
    for (int n = 0; n < NST; ++n) acoef[n] = -__expf(A_log[d * NST + n]);
    const float a0 = acoef[0];
    const bool structured = a_structured(acoef);

    const float4* B4 = (const float4*)(Bp + (size_t)rowbase * NST);
    const float* s1p = s1 + rowbase;
    const float* xp = x + (size_t)rowbase * DDIM + d;

    float h[NST];
    #pragma unroll
    for (int n = 0; n < NST; ++n) h[n] = 0.f;
    float S = 0.f;

    if (structured) {
        #pragma unroll 4
        for (int l = 0; l < CS; ++l) {
            const float delta = softplus_f(fmaf(s1p[l], wd, bdv));
            S += delta;
            float e[NST];
            powers16(__expf(delta * a0), e);
            const float dx = delta * xp[(size_t)l * DDIM];
            const float4 b0 = B4[l * 4 + 0], b1v = B4[l * 4 + 1];
            const float4 b2 = B4[l * 4 + 2], b3v = B4[l * 4 + 3];
            const float bv[NST] = {b0.x, b0.y, b0.z, b0.w, b1v.x, b1v.y, b1v.z, b1v.w,
                                   b2.x, b2.y, b2.z, b2.w, b3v.x, b3v.y, b3v.z, b3v.w};
            #pragma unroll
            for (int n = 0; n < NST; ++n) h[n] = fmaf(e[n], h[n], dx * bv[n]);
        }
    } else {
        #pragma unroll 4
        for (int l = 0; l < CS; ++l) {
            const float delta = softplus_f(fmaf(s1p[l], wd, bdv));
            S += delta;
            float e[NST];
            #pragma unroll
            for (int n = 0; n < NST; ++n) e[n] = __expf(delta * acoef[n]);
            const float dx = delta * xp[(size_t)l * DDIM];
            const float4 b0 = B4[l * 4 + 0], b1v = B4[l * 4 + 1];
            const float4 b2 = B4[l * 4 + 2], b3v = B4[l * 4 + 3];
            const float bv[NST] = {b0.x, b0.y, b0.z, b0.w, b1v.x, b1v.y, b1v.z, b1v.w,
                                   b2.x, b2.y, b2.z, b2.w, b3v.x, b3v.y, b3v.z, b3v.w};
            #pragma unroll
            for (int n = 0; n < NST; ++n) h[n] = fmaf(e[n], h[n], dx * bv[n]);
        }
    }
    // chunk multiplier is exp(acoef[n]*S) -- store S only, recompute in combine
    Ssum[((size_t)b * NC + c) * DDIM + d] = S;
    const size_t gbase = (((size_t)b * NC + c) * DDIM + d) * NST;
    float4* Q4 = (float4*)(Q + gbase);
    #pragma unroll
    for (int q = 0; q < 4; ++q)
        Q4[q] = make_float4(h[q * 4], h[q * 4 + 1], h[q * 4 + 2], h[q * 4 + 3]);
}

// 64-thread blocks: 768 blocks spread the serial chains over all CUs
__global__ __launch_bounds__(64) void combine_kernel(
    const float* __restrict__ A_log,
    const float* __restrict__ Ssum, const float* __restrict__ Q,
    float* __restrict__ Hin, int NC)
{
    const int idx = blockIdx.x * 64 + threadIdx.x;   // over B*D*N
    const int b = idx / (DDIM * NST);
    const int r = idx % (DDIM * NST);
    const int d = r / NST;
    const float acoef = -__expf(A_log[r]);
    float h = 0.f;
    #pragma unroll 4
    for (int c = 0; c < NC; ++c) {
        const size_t base = (size_t)(b * NC + c);
        const float Sg = Ssum[base * DDIM + d];
        const float qg = Q[base * (DDIM * NST) + r];
        Hin[base * (DDIM * NST) + r] = h;
        h = fmaf(__expf(acoef * Sg), h, qg);
    }
}

template <int CS>
__global__ __launch_bounds__(256) void pass2_kernel(
    const float* __restrict__ x, const float* __restrict__ A_log,
    const float* __restrict__ Wd, const float* __restrict__ bd,
    const float* __restrict__ Bp, const float* __restrict__ Cc,
    const float* __restrict__ s1, const float* __restrict__ Hin,
    float* __restrict__ out)
{
    const int tid = threadIdx.x;
    const int d = blockIdx.x * 256 + tid;
    const int c = blockIdx.y, b = blockIdx.z;
    const int NC = gridDim.y;
    const int rowbase = b * LSEQ + c * CS;

    const float wd = Wd[d], bdv = bd[d];
    float acoef[NST];
    #pragma unroll
    for (int n = 0; n < NST; ++n) acoef[n] = -__expf(A_log[d * NST + n]);
    const float a0 = acoef[0];
    const bool structured = a_structured(acoef);

    const float4* B4 = (const float4*)(Bp + (size_t)rowbase * NST);
    const float4* C4 = (const float4*)(Cc + (size_t)rowbase * NST);
    const float* s1p = s1 + rowbase;
    const float* xp = x + (size_t)rowbase * DDIM + d;
    float* yp = out + (size_t)rowbase * DDIM + d;

    float h[NST];
    const size_t gbase = (((size_t)b * NC + c) * DDIM + d) * NST;
    const float4* H4 = (const float4*)(Hin + gbase);
    #pragma unroll
    for (int q = 0; q < 4; ++q) {
        const float4 hv = H4[q];
        h[q * 4] = hv.x; h[q * 4 + 1] = hv.y; h[q * 4 + 2] = hv.z; h[q * 4 + 3] = hv.w;
    }

    if (structured) {
        #pragma unroll 4
        for (int l = 0; l < CS; ++l) {
            const float delta = softplus_f(fmaf(s1p[l], wd, bdv));
            float e[NST];
            powers16(__expf(delta * a0), e);
            const float dx = delta * xp[(size_t)l * DDIM];
            const float4 b0 = B4[l * 4 + 0], b1v = B4[l * 4 + 1];
            const float4 b2 = B4[l * 4 + 2], b3v = B4[l * 4 + 3];
            const float4 c0 = C4[l * 4 + 0], c1v = C4[l * 4 + 1];
            const float4 c2 = C4[l * 4 + 2], c3v = C4[l * 4 + 3];
            const float bv[NST] = {b0.x, b0.y, b0.z, b0.w, b1v.x, b1v.y, b1v.z, b1v.w,
                                   b2.x, b2.y, b2.z, b2.w, b3v.x, b3v.y, b3v.z, b3v.w};
            const float cv[NST] = {c0.x, c0.y, c0.z, c0.w, c1v.x, c1v.y, c1v.z, c1v.w,
                                   c2.x, c2.y, c2.z, c2.w, c3v.x, c3v.y, c3v.z, c3v.w};
            float y = 0.f;
            #pragma unroll
            for (int n = 0; n < NST; ++n) {
                h[n] = fmaf(e[n], h[n], dx * bv[n]);
                y = fmaf(h[n], cv[n], y);
            }
            yp[(size_t)l * DDIM] = y;
        }
    } else {
        #pragma unroll 4
        for (int l = 0; l < CS; ++l) {
            const float delta = softplus_f(fmaf(s1p[l], wd, bdv));
            float e[NST];
            #pragma unroll
            for (int n = 0; n < NST; ++n) e[n] = __expf(delta * acoef[n]);
            const float dx = delta * xp[(size_t)l * DDIM];
            const float4 b0 = B4[l * 4 + 0], b1v = B4[l * 4 + 1];
            const float4 b2 = B4[l * 4 + 2], b3v = B4[l * 4 + 3];
            const float4 c0 = C4[l * 4 + 0], c1v = C4[l * 4 + 1];
            const float4 c2 = C4[l * 4 + 2], c3v = C4[l * 4 + 3];
            const float bv[NST] = {b0.x, b0.y, b0.z, b0.w, b1v.x, b1v.y, b1v.z, b1v.w,
                                   b2.x, b2.y, b2.z, b2.w, b3v.x, b3v.y, b3v.z, b3v.w};
            const float cv[NST] = {c0.x, c0.y, c0.z, c0.w, c1v.x, c1v.y, c1v.z, c1v.w,
                                   c2.x, c2.y, c2.z, c2.w, c3v.x, c3v.y, c3v.z, c3v.w};
            float y = 0.f;
            #pragma unroll
            for (int n = 0; n < NST; ++n) {
                h[n] = fmaf(e[n], h[n], dx * bv[n]);
                y = fmaf(h[n], cv[n], y);
            }
            yp[(size_t)l * DDIM] = y;
        }
    }
}

extern "C" void kernel_launch(void* const* d_in, const int* in_sizes, int n_in,
                              void* d_out, int out_size, void* d_ws, size_t ws_size,
                              hipStream_t stream) {
    const float* x     = (const float*)d_in[0];
    const float* A_log = (const float*)d_in[1];
    const float* Wb    = (const float*)d_in[2];
    const float* bb    = (const float*)d_in[3];
    const float* Wc    = (const float*)d_in[4];
    const float* bc    = (const float*)d_in[5];
    const float* W1    = (const float*)d_in[6];
    const float* b1    = (const float*)d_in[7];
    const float* Wd    = (const float*)d_in[8];
    const float* bd    = (const float*)d_in[9];
    float* out = (float*)d_out;

    float* ws = (float*)d_ws;
    const size_t partN = (size_t)KSPLIT * NJ * NROW;   // 4.33M
    const size_t BpN = (size_t)NROW * NST;             // 131072
    const size_t s1N = (size_t)NROW;                   // 8192

    int NC = 64;
    while (NC > 16) {
        size_t agg_ = (size_t)B_SZ * NC * DDIM * NST;
        size_t sN_ = (size_t)B_SZ * NC * DDIM;
        size_t need = (partN + 2 * BpN + s1N + sN_ + 2 * agg_) * sizeof(float);
        if (need <= ws_size) break;
        NC >>= 1;
    }
    const int CS = LSEQ / NC;

    float* part = ws;
    float* Bp   = part + partN;
    float* Cc   = Bp + BpN;
    float* s1   = Cc + BpN;
    float* Ssum = s1 + s1N;
    const size_t sN = (size_t)B_SZ * NC * DDIM;
    const size_t agg = (size_t)B_SZ * NC * DDIM * NST;
    float* Q    = Ssum + sN;
    float* Hin  = Q + agg;

    dim3 gproj(NROW / 256, KSPLIT);
    proj_part_kernel<<<gproj, 256, 0, stream>>>(x, Wb, Wc, W1, part);
    proj_reduce_kernel<<<(NJ * NROW) / 256, 256, 0, stream>>>(part, bb, bc, b1, Bp, Cc, s1);

    dim3 gscan(DDIM / 256, NC, B_SZ);
    if (CS == 32)
        pass1_kernel<32><<<gscan, 256, 0, stream>>>(x, A_log, Wd, bd, Bp, s1, Ssum, Q);
    else if (CS == 64)
        pass1_kernel<64><<<gscan, 256, 0, stream>>>(x, A_log, Wd, bd, Bp, s1, Ssum, Q);
    else
        pass1_kernel<128><<<gscan, 256, 0, stream>>>(x, A_log, Wd, bd, Bp, s1, Ssum, Q);

    combine_kernel<<<(B_SZ * DDIM * NST) / 64, 64, 0, stream>>>(A_log, Ssum, Q, Hin, NC);

    if (CS == 32)
        pass2_kernel<32><<<gscan, 256, 0, stream>>>(x, A_log, Wd, bd, Bp, Cc, s1, Hin, out);
    else if (CS == 64)
        pass2_kernel<64><<<gscan, 256, 0, stream>>>(x, A_log, Wd, bd, Bp, Cc, s1, Hin, out);
    else
        pass2_kernel<128><<<gscan, 256, 0, stream>>>(x, A_log, Wd, bd, Bp, Cc, s1, Hin, out);
}